// Round 1
// baseline (176.543 us; speedup 1.0000x reference)
//
#include <hip/hip_runtime.h>
#include <cmath>

namespace {
constexpr int kN  = 16;
constexpr int kC  = 128;
constexpr int kH  = 48;
constexpr int kW  = 48;
constexpr int kHW = kH * kW;        // 2304
constexpr int kC2 = kC / 2;         // 64
constexpr int kK9 = 3 * kC / 2;     // 192
constexpr int kPC = 144;            // p-chunk for correlation GEMM (9 x 16)
constexpr int kNPC = kHW / kPC;     // 16 chunks
}

// ---------------------------------------------------------------------------
// t1[n,q] = max_c x[n,c,q]   (channel max; coalesced along q)
// ---------------------------------------------------------------------------
__global__ void k_t1(const float* __restrict__ x, float* __restrict__ t1) {
  int idx = blockIdx.x * blockDim.x + threadIdx.x;
  if (idx >= kN * kHW) return;
  int n = idx / kHW;
  int q = idx - n * kHW;
  const float* xp = x + (size_t)n * kC * kHW + q;
  float m = xp[0];
#pragma unroll 8
  for (int c = 1; c < kC; ++c) m = fmaxf(m, xp[(size_t)c * kHW]);
  t1[idx] = m;
}

// ---------------------------------------------------------------------------
// t5[n,c,q] = p5[c,q] * max(-x[n,c,h,w], -x[n,c,h,(w-1)%W])
// ---------------------------------------------------------------------------
__global__ void k_t5(const float* __restrict__ x, const float* __restrict__ p5,
                     float* __restrict__ t5) {
  int idx = blockIdx.x * blockDim.x + threadIdx.x;
  if (idx >= kN * kC * kHW) return;
  int q = idx % kHW;
  int c = (idx / kHW) % kC;
  int w = q % kW;
  float xv = x[idx];
  float xprev = x[idx + ((w == 0) ? (kW - 1) : -1)];
  float t4 = fmaxf(-xv, -xprev);
  t5[idx] = p5[c * kHW + q] * t4;
}

// ---------------------------------------------------------------------------
// t8[n,c2,h,w] = sum_{j=0..4} w8[c2*5+j] * t1[n,h,w+3j-6]   (zero-pad width)
// ---------------------------------------------------------------------------
__global__ void k_t8(const float* __restrict__ t1, const float* __restrict__ w8,
                     float* __restrict__ t8) {
  int idx = blockIdx.x * blockDim.x + threadIdx.x;
  if (idx >= kN * kC2 * kHW) return;
  int q = idx % kHW;
  int nc = idx / kHW;
  int c2 = nc % kC2;
  int n = nc / kC2;
  int h = q / kW, w = q - h * kW;
  const float* trow = t1 + (size_t)n * kHW + h * kW;
  float acc = 0.f;
#pragma unroll
  for (int j = 0; j < 5; ++j) {
    int ww = w + 3 * j - 6;
    if (ww >= 0 && ww < kW) acc = fmaf(w8[c2 * 5 + j], trow[ww], acc);
  }
  t8[idx] = acc;
}

// ---------------------------------------------------------------------------
// t9[n, c2*3+k, h, w] = t8[n, c2, h+2k-2, w]   (zero-pad rows)
// ---------------------------------------------------------------------------
__global__ void k_t9(const float* __restrict__ t8, float* __restrict__ t9) {
  int idx = blockIdx.x * blockDim.x + threadIdx.x;
  if (idx >= kN * kK9 * kHW) return;
  int q = idx % kHW;
  int nk = idx / kHW;
  int k = nk % kK9;
  int n = nk / kK9;
  int c2 = k / 3, kk = k - c2 * 3;
  int h = q / kW, w = q - h * kW;
  int hh = h + 2 * kk - 2;
  float v = 0.f;
  if (hh >= 0 && hh < kH) v = t8[((size_t)n * kC2 + c2) * kHW + hh * kW + w];
  t9[idx] = v;
}

// ---------------------------------------------------------------------------
// Generic M=128 x (p-tile 64) GEMM, K templated (128 or 192), BK=16.
// Out[n,m,p] = sum_k Ag[m,k] * B[n,k,p]
// MODE 0: plain store (t6)
// MODE 1: t12 epilogue: Out[n,(m+1)%128,p] = max(X[n,(m+1)%128,p], acc)
// MODE 2: A is per-batch (A + n*128*K), store scale*acc (final output)
// ---------------------------------------------------------------------------
template <int K, int MODE>
__global__ __launch_bounds__(256)
void k_gemm(const float* __restrict__ A, const float* __restrict__ B,
            const float* __restrict__ X, float* __restrict__ Out, float scale) {
  __shared__ float As[16][kC];   // 8 KB, [k][m]
  __shared__ float Bs[16][64];   // 4 KB, [k][p]
  const int tid = threadIdx.x;
  const int n = blockIdx.y;
  const int pbase = blockIdx.x * 64;
  const float* Ag = (MODE == 2) ? (A + (size_t)n * kC * K) : A;
  const float* Bg = B + (size_t)n * K * kHW + pbase;
  const int ty = tid >> 4;   // 0..15 -> 8 m-rows each
  const int tx = tid & 15;   // 0..15 -> 4 p-cols each

  float acc[8][4];
#pragma unroll
  for (int i = 0; i < 8; ++i)
#pragma unroll
    for (int j = 0; j < 4; ++j) acc[i][j] = 0.f;

  for (int k0 = 0; k0 < K; k0 += 16) {
    // A tile 128x16: thread loads 8 contiguous k
    {
      const int m = tid >> 1;
      const int kh = (tid & 1) * 8;
      const float* src = Ag + (size_t)m * K + k0 + kh;
#pragma unroll
      for (int i = 0; i < 8; ++i) As[kh + i][m] = src[i];
    }
    // B tile 16x64: 4 elements per thread, coalesced along p
#pragma unroll
    for (int i = 0; i < 4; ++i) {
      const int idx = tid + i * 256;
      const int kk = idx >> 6, p = idx & 63;
      Bs[kk][p] = Bg[(size_t)(k0 + kk) * kHW + p];
    }
    __syncthreads();
#pragma unroll
    for (int kk = 0; kk < 16; ++kk) {
      float a[8], b[4];
#pragma unroll
      for (int i = 0; i < 8; ++i) a[i] = As[kk][ty * 8 + i];
#pragma unroll
      for (int j = 0; j < 4; ++j) b[j] = Bs[kk][tx * 4 + j];
#pragma unroll
      for (int i = 0; i < 8; ++i)
#pragma unroll
        for (int j = 0; j < 4; ++j) acc[i][j] = fmaf(a[i], b[j], acc[i][j]);
    }
    __syncthreads();
  }

#pragma unroll
  for (int i = 0; i < 8; ++i) {
    const int m = ty * 8 + i;
#pragma unroll
    for (int j = 0; j < 4; ++j) {
      const int p = pbase + tx * 4 + j;
      if (MODE == 0) {
        Out[((size_t)n * kC + m) * kHW + p] = acc[i][j];
      } else if (MODE == 1) {
        const int mo = (m + 1) & (kC - 1);   // t12[c] = max(x[c], t10[c-1])
        const size_t o = ((size_t)n * kC + mo) * kHW + p;
        Out[o] = fmaxf(X[o], acc[i][j]);
      } else {
        Out[((size_t)n * kC + m) * kHW + p] = scale * acc[i][j];
      }
    }
  }
}

// ---------------------------------------------------------------------------
// Correlation GEMM: partial M[n,c,c'] = sum_{p in chunk} t12[n,c,p] t6[n,c',p]
// Each block: full 128x128 output for one (n, p-chunk of 144).
// Writes its own partial slab -> deterministic (no fp atomics).
// ---------------------------------------------------------------------------
__global__ __launch_bounds__(256)
void k_corr(const float* __restrict__ t12, const float* __restrict__ t6,
            float* __restrict__ part) {
  __shared__ float As[16][kC];   // [p][c]  (t12)
  __shared__ float Bs[16][kC];   // [p][c'] (t6)
  const int tid = threadIdx.x;
  const int n = blockIdx.y;
  const int p0 = blockIdx.x * kPC;
  const float* Ag = t12 + (size_t)n * kC * kHW;
  const float* Bg = t6 + (size_t)n * kC * kHW;
  const int ty = tid >> 4;
  const int tx = tid & 15;

  float acc[8][8];
#pragma unroll
  for (int i = 0; i < 8; ++i)
#pragma unroll
    for (int j = 0; j < 8; ++j) acc[i][j] = 0.f;

  for (int kt = 0; kt < kPC; kt += 16) {
    const int pb = p0 + kt;
    const int c = tid >> 1;
    const int i0 = (tid & 1) * 8;
    const float* a = Ag + (size_t)c * kHW + pb + i0;
    const float* b = Bg + (size_t)c * kHW + pb + i0;
#pragma unroll
    for (int i = 0; i < 8; ++i) As[i0 + i][c] = a[i];
#pragma unroll
    for (int i = 0; i < 8; ++i) Bs[i0 + i][c] = b[i];
    __syncthreads();
#pragma unroll
    for (int kk = 0; kk < 16; ++kk) {
      float av[8], bv[8];
#pragma unroll
      for (int i = 0; i < 8; ++i) av[i] = As[kk][ty * 8 + i];
#pragma unroll
      for (int j = 0; j < 8; ++j) bv[j] = Bs[kk][tx * 8 + j];
#pragma unroll
      for (int i = 0; i < 8; ++i)
#pragma unroll
        for (int j = 0; j < 8; ++j) acc[i][j] = fmaf(av[i], bv[j], acc[i][j]);
    }
    __syncthreads();
  }

  float* dst = part + ((size_t)blockIdx.x * kN + n) * (kC * kC);
#pragma unroll
  for (int i = 0; i < 8; ++i)
#pragma unroll
    for (int j = 0; j < 8; ++j)
      dst[(ty * 8 + i) * kC + tx * 8 + j] = acc[i][j];
}

// ---------------------------------------------------------------------------
// Reduce the kNPC partial slabs into M[n,c,c']
// ---------------------------------------------------------------------------
__global__ void k_redM(const float* __restrict__ part, float* __restrict__ M) {
  int idx = blockIdx.x * blockDim.x + threadIdx.x;
  if (idx >= kN * kC * kC) return;
  int n = idx / (kC * kC);
  int r = idx - n * (kC * kC);
  float s = 0.f;
#pragma unroll
  for (int ch = 0; ch < kNPC; ++ch)
    s += part[((size_t)ch * kN + n) * (kC * kC) + r];
  M[idx] = s;
}

// ---------------------------------------------------------------------------
extern "C" void kernel_launch(void* const* d_in, const int* in_sizes, int n_in,
                              void* d_out, int out_size, void* d_ws, size_t ws_size,
                              hipStream_t stream) {
  const float* x   = (const float*)d_in[0];
  const float* p5  = (const float*)d_in[1];
  const float* w6  = (const float*)d_in[2];
  const float* w8  = (const float*)d_in[3];
  const float* w10 = (const float*)d_in[4];
  float* out = (float*)d_out;

  float* ws = (float*)d_ws;
  // layout (floats); t12 reuses t5 (dead after t6 GEMM); part/M reuse t9
  // (dead after t10 GEMM). Peak usage ~76.7 MB.
  float* t5b = ws;                         // 16*128*2304 = 4718592
  float* t6b = t5b + (size_t)kN * kC * kHW;  // 4718592
  float* t8b = t6b + (size_t)kN * kC * kHW;  // 16*64*2304 = 2359296
  float* t9b = t8b + (size_t)kN * kC2 * kHW; // 16*192*2304 = 7077888
  float* t1b = t9b + (size_t)kN * kK9 * kHW; // 36864
  float* t12b = t5b;                        // alias: t5 dead after t6 GEMM
  float* partb = t9b;                       // alias: t9 dead after t10 GEMM (4194304)
  float* Mb = t9b + (size_t)kNPC * kN * kC * kC; // 262144 (still inside t9 region)

  const float scale = 1.0f / (sqrtf((float)kC) * sqrtf((float)kHW));

  // 1) channel max
  k_t1<<<(kN * kHW + 255) / 256, 256, 0, stream>>>(x, t1b);
  // 2) t5
  k_t5<<<(kN * kC * kHW + 255) / 256, 256, 0, stream>>>(x, p5, t5b);
  // 3) t6 = w6 @ t5
  k_gemm<kC, 0><<<dim3(kHW / 64, kN), 256, 0, stream>>>(w6, t5b, nullptr, t6b, 1.f);
  // 4) t8 (dilated 1x5 conv on t1)
  k_t8<<<(kN * kC2 * kHW + 255) / 256, 256, 0, stream>>>(t1b, w8, t8b);
  // 5) t9 (row unfold)
  k_t9<<<(kN * kK9 * kHW + 255) / 256, 256, 0, stream>>>(t8b, t9b);
  // 6) t10 = w10 @ t9, fused t12 = max(x, roll(t10,1,ch)) epilogue
  k_gemm<kK9, 1><<<dim3(kHW / 64, kN), 256, 0, stream>>>(w10, t9b, x, t12b, 1.f);
  // 7) M partials: t12 @ t6^T over p-chunks
  k_corr<<<dim3(kNPC, kN), 256, 0, stream>>>(t12b, t6b, partb);
  // 8) reduce partials
  k_redM<<<(kN * kC * kC + 255) / 256, 256, 0, stream>>>(partb, Mb);
  // 9) out = scale * M @ x
  k_gemm<kC, 2><<<dim3(kHW / 64, kN), 256, 0, stream>>>(Mb, x, nullptr, out, scale);
}

// Round 2
// 155.930 us; speedup vs baseline: 1.1322x; 1.1322x over previous
//
#include <hip/hip_runtime.h>
#include <cmath>

typedef short bf16x8 __attribute__((ext_vector_type(8)));
typedef float f32x4 __attribute__((ext_vector_type(4)));

namespace {
constexpr int kN   = 16;
constexpr int kC   = 128;
constexpr int kH   = 48;
constexpr int kW   = 48;
constexpr int kHW  = kH * kW;      // 2304
constexpr int kK9  = 192;          // 3*C/2
constexpr int kNPC = 18;           // correlation p-chunks
constexpr int kPCH = kHW / kNPC;   // 128
}

__device__ __forceinline__ unsigned short f2b(float f) {
  unsigned u = __builtin_bit_cast(unsigned, f);
  u = (u + 0x7FFFu + ((u >> 16) & 1u)) >> 16;   // RTNE
  return (unsigned short)u;
}

// ---------------------------------------------------------------------------
// Convert weights to bf16. w6: 128x128, w10: 128x192 (row-major [o][k]).
// ---------------------------------------------------------------------------
__global__ void k_wcvt(const float* __restrict__ w6, const float* __restrict__ w10,
                       unsigned short* __restrict__ w6b, unsigned short* __restrict__ w10b) {
  const int i = blockIdx.x * 256 + threadIdx.x;
  if (i < kC * kC) w6b[i] = f2b(w6[i]);
  const int j = i - kC * kC;
  if (j >= 0 && j < kC * kK9) w10b[j] = f2b(w10[j]);
}

// ---------------------------------------------------------------------------
// Fused: xT[n][q][c] = bf16(x), t5T[n][q][c] = bf16(p5*max(-x, -x_wprev)),
//        t1[n][q] = max_c x.   Block = 128 c (fastest) x 2 q.
// ---------------------------------------------------------------------------
__global__ __launch_bounds__(256)
void k_xt5(const float* __restrict__ x, const float* __restrict__ p5,
           unsigned short* __restrict__ xT, unsigned short* __restrict__ t5T,
           float* __restrict__ t1) {
  const int tid = threadIdx.x;
  const int c = tid & 127;
  const int qi = tid >> 7;
  const int g = blockIdx.x * 2 + qi;          // n*kHW + q
  const int n = g / kHW, q = g - n * kHW;
  const int w = q % kW;
  const size_t xo = ((size_t)n * kC + c) * kHW + q;
  const float xv = x[xo];
  const float xp = x[xo + ((w == 0) ? (kW - 1) : -1)];
  const float t5 = p5[c * kHW + q] * fmaxf(-xv, -xp);
  const size_t to = (size_t)g * kC + c;
  xT[to] = f2b(xv);
  t5T[to] = f2b(t5);
  // channel max (128 c = 2 waves per q)
  float m = xv;
#pragma unroll
  for (int off = 32; off >= 1; off >>= 1)
    m = fmaxf(m, __shfl_xor(m, off, 64));
  __shared__ float red[4];
  if ((tid & 63) == 0) red[tid >> 6] = m;
  __syncthreads();
  if (tid < 2) t1[blockIdx.x * 2 + tid] = fmaxf(red[2 * tid], red[2 * tid + 1]);
}

// ---------------------------------------------------------------------------
// t9T[n][q][k] (bf16, k=0..191 contiguous), fusing the dilated 1x5 conv on t1
// and the (3,1)-unfold: k=(c2,kk), hh=h+2kk-2,
//   val = sum_j w8[c2,j] * t1[n, hh, w+3j-6]   (zero outside)
// ---------------------------------------------------------------------------
__global__ void k_t9T(const float* __restrict__ t1, const float* __restrict__ w8,
                      unsigned short* __restrict__ t9T) {
  const int idx = blockIdx.x * 256 + threadIdx.x;
  const int k = idx % kK9;
  const int g = idx / kK9;                    // n*kHW + q
  const int q = g % kHW;
  const int n = g / kHW;
  const int c2 = k / 3, kk = k - 3 * c2;
  const int h = q / kW, w = q - h * kW;
  const int hh = h + 2 * kk - 2;
  float v = 0.f;
  if (hh >= 0 && hh < kH) {
    const float* tr = t1 + (size_t)n * kHW + hh * kW;
#pragma unroll
    for (int j = 0; j < 5; ++j) {
      const int ww = w + 3 * j - 6;
      if (ww >= 0 && ww < kW) v = fmaf(w8[c2 * 5 + j], tr[ww], v);
    }
  }
  t9T[idx] = f2b(v);
}

// ---------------------------------------------------------------------------
// bf16 MFMA GEMM: Out[n,m,q] = sum_k A[m,k]*B[n,q,k],  M=128, q-tile=64.
// A: [128][K] bf16 (MODE 2: per-batch, A + n*128*K). B: [n][q][K] bf16.
// MODE 0: store bf16 (t6). MODE 1: t12 = bf16(max(x[(m+1)%128], acc)).
// MODE 2: store fp32 scale*acc (final out).
// 4 waves; wave = 32 rows x 64 cols (2x4 16x16 tiles).
// ---------------------------------------------------------------------------
template <int K, int MODE>
__global__ __launch_bounds__(256)
void k_mm(const unsigned short* __restrict__ A, const unsigned short* __restrict__ B,
          const float* __restrict__ X, void* __restrict__ Out, float scale) {
  constexpr int P  = K + 8;   // padded A row (bf16)
  constexpr int BP = 72;      // padded B row for 64-k chunk
  __shared__ unsigned short As[kC * P];
  __shared__ unsigned short Bs[64 * BP];
  const int tid = threadIdx.x;
  const int n = blockIdx.y;
  const int qbase = blockIdx.x * 64;
  const unsigned short* Ag = (MODE == 2) ? A + (size_t)n * kC * K : A;
  const unsigned short* Bg = B + ((size_t)n * kHW + qbase) * K;

  // stage all of A (128 x K)
  {
    const int m = tid >> 1, hf = tid & 1;
    const unsigned short* src = Ag + (size_t)m * K + hf * (K / 2);
    unsigned short* dst = &As[m * P + hf * (K / 2)];
#pragma unroll
    for (int i = 0; i < K / 16; ++i)
      *(bf16x8*)(dst + 8 * i) = *(const bf16x8*)(src + 8 * i);
  }

  const int wv = tid >> 6, lane = tid & 63;
  const int lr = lane & 15, lk = (lane >> 4) * 8;

  f32x4 acc[2][4];
#pragma unroll
  for (int i = 0; i < 2; ++i)
#pragma unroll
    for (int j = 0; j < 4; ++j) acc[i][j] = f32x4{0.f, 0.f, 0.f, 0.f};

  for (int ks = 0; ks < K; ks += 64) {
    if (ks) __syncthreads();
    {  // stage B chunk (64 q x 64 k)
      const int q = tid >> 2, seg = tid & 3;
      const unsigned short* src = Bg + (size_t)q * K + ks + seg * 16;
      unsigned short* dst = &Bs[q * BP + seg * 16];
      *(bf16x8*)dst = *(const bf16x8*)src;
      *(bf16x8*)(dst + 8) = *(const bf16x8*)(src + 8);
    }
    __syncthreads();
#pragma unroll
    for (int kt = 0; kt < 2; ++kt) {
      bf16x8 a[2], b[4];
#pragma unroll
      for (int mt = 0; mt < 2; ++mt)
        a[mt] = *(const bf16x8*)&As[(32 * wv + 16 * mt + lr) * P + ks + kt * 32 + lk];
#pragma unroll
      for (int nt = 0; nt < 4; ++nt)
        b[nt] = *(const bf16x8*)&Bs[(16 * nt + lr) * BP + kt * 32 + lk];
#pragma unroll
      for (int mt = 0; mt < 2; ++mt)
#pragma unroll
        for (int nt = 0; nt < 4; ++nt)
          acc[mt][nt] = __builtin_amdgcn_mfma_f32_16x16x32_bf16(
              a[mt], b[nt], acc[mt][nt], 0, 0, 0);
    }
  }

#pragma unroll
  for (int mt = 0; mt < 2; ++mt)
#pragma unroll
    for (int nt = 0; nt < 4; ++nt) {
      const int q = qbase + 16 * nt + lr;
#pragma unroll
      for (int r = 0; r < 4; ++r) {
        const int m = 32 * wv + 16 * mt + 4 * (lane >> 4) + r;
        const float v = acc[mt][nt][r];
        if (MODE == 0) {
          ((unsigned short*)Out)[((size_t)n * kC + m) * kHW + q] = f2b(v);
        } else if (MODE == 1) {
          const int mo = (m + 1) & (kC - 1);     // t11[c] = t10[c-1]
          const size_t o = ((size_t)n * kC + mo) * kHW + q;
          ((unsigned short*)Out)[o] = f2b(fmaxf(X[o], v));
        } else {
          ((float*)Out)[((size_t)n * kC + m) * kHW + q] = scale * v;
        }
      }
    }
}

// ---------------------------------------------------------------------------
// Correlation partials: part[chunk,n,c,c'] = sum_{p in chunk} t12[n,c,p]*t6[n,c',p]
// Both operands in natural [c][p] bf16 layout. Block: 128x128 out, 4 waves 2x2.
// ---------------------------------------------------------------------------
__global__ __launch_bounds__(256)
void k_corr(const unsigned short* __restrict__ t12, const unsigned short* __restrict__ t6,
            float* __restrict__ part) {
  constexpr int PP = 40;
  __shared__ unsigned short As[kC * PP];
  __shared__ unsigned short Bs[kC * PP];
  const int tid = threadIdx.x;
  const int n = blockIdx.y;
  const int p0 = blockIdx.x * kPCH;
  const unsigned short* Ag = t12 + (size_t)n * kC * kHW + p0;
  const unsigned short* Bg = t6  + (size_t)n * kC * kHW + p0;
  const int wv = tid >> 6, lane = tid & 63;
  const int lr = lane & 15, lk = (lane >> 4) * 8;
  const int wr = (wv >> 1) * 64, wc = (wv & 1) * 64;

  f32x4 acc[4][4];
#pragma unroll
  for (int i = 0; i < 4; ++i)
#pragma unroll
    for (int j = 0; j < 4; ++j) acc[i][j] = f32x4{0.f, 0.f, 0.f, 0.f};

  for (int ks = 0; ks < kPCH; ks += 32) {
    if (ks) __syncthreads();
    {  // stage 128 x 32 slabs of both operands
      const int c = tid >> 1, hf = tid & 1;
      const unsigned short* sa = Ag + (size_t)c * kHW + ks + hf * 16;
      const unsigned short* sb = Bg + (size_t)c * kHW + ks + hf * 16;
      unsigned short* da = &As[c * PP + hf * 16];
      unsigned short* db = &Bs[c * PP + hf * 16];
      *(bf16x8*)da = *(const bf16x8*)sa;  *(bf16x8*)(da + 8) = *(const bf16x8*)(sa + 8);
      *(bf16x8*)db = *(const bf16x8*)sb;  *(bf16x8*)(db + 8) = *(const bf16x8*)(sb + 8);
    }
    __syncthreads();
    bf16x8 a[4], b[4];
#pragma unroll
    for (int i = 0; i < 4; ++i) {
      a[i] = *(const bf16x8*)&As[(wr + 16 * i + lr) * PP + lk];
      b[i] = *(const bf16x8*)&Bs[(wc + 16 * i + lr) * PP + lk];
    }
#pragma unroll
    for (int i = 0; i < 4; ++i)
#pragma unroll
      for (int j = 0; j < 4; ++j)
        acc[i][j] = __builtin_amdgcn_mfma_f32_16x16x32_bf16(a[i], b[j], acc[i][j], 0, 0, 0);
  }

  float* dst = part + ((size_t)blockIdx.x * kN + n) * (kC * kC);
#pragma unroll
  for (int i = 0; i < 4; ++i)
#pragma unroll
    for (int j = 0; j < 4; ++j)
#pragma unroll
      for (int r = 0; r < 4; ++r)
        dst[(wr + 16 * i + 4 * (lane >> 4) + r) * kC + wc + 16 * j + lr] = acc[i][j][r];
}

// ---------------------------------------------------------------------------
// Reduce kNPC partial slabs -> M bf16 [n][c][c']
// ---------------------------------------------------------------------------
__global__ void k_redM(const float* __restrict__ part, unsigned short* __restrict__ M) {
  const int idx = blockIdx.x * 256 + threadIdx.x;
  const int n = idx >> 14, r = idx & 16383;
  float s = 0.f;
#pragma unroll
  for (int ch = 0; ch < kNPC; ++ch)
    s += part[(((size_t)ch * kN + n) << 14) + r];
  M[idx] = f2b(s);
}

// ---------------------------------------------------------------------------
extern "C" void kernel_launch(void* const* d_in, const int* in_sizes, int n_in,
                              void* d_out, int out_size, void* d_ws, size_t ws_size,
                              hipStream_t stream) {
  const float* x   = (const float*)d_in[0];
  const float* p5  = (const float*)d_in[1];
  const float* w6  = (const float*)d_in[2];
  const float* w8  = (const float*)d_in[3];
  const float* w10 = (const float*)d_in[4];
  float* out = (float*)d_out;

  char* ws = (char*)d_ws;                                  // byte offsets
  unsigned short* xT   = (unsigned short*)(ws);            //  9,437,184
  unsigned short* t5T  = (unsigned short*)(ws + 9437184);  //  9,437,184
  unsigned short* t6b  = (unsigned short*)(ws + 18874368); //  9,437,184
  unsigned short* t12b = (unsigned short*)(ws + 28311552); //  9,437,184
  unsigned short* t9Tb = (unsigned short*)(ws + 37748736); // 14,155,776
  float*          part = (float*)(ws + 51904512);          // 18,874,368
  unsigned short* Mb   = (unsigned short*)(ws + 70778880); //    524,288
  float*          t1b  = (float*)(ws + 71303168);          //    147,456
  unsigned short* w6b  = (unsigned short*)(ws + 71450624); //     32,768
  unsigned short* w10b = (unsigned short*)(ws + 71483392); //     49,152  (end ~71.5 MB)

  const float scale = 1.0f / (sqrtf((float)kC) * sqrtf((float)kHW));

  k_wcvt<<<(kC * kC + kC * kK9 + 255) / 256, 256, 0, stream>>>(w6, w10, w6b, w10b);
  k_xt5<<<kN * kHW / 2, 256, 0, stream>>>(x, p5, xT, t5T, t1b);
  k_t9T<<<kN * kHW * kK9 / 256, 256, 0, stream>>>(t1b, w8, t9Tb);
  k_mm<128, 0><<<dim3(kHW / 64, kN), 256, 0, stream>>>(w6b, t5T, nullptr, t6b, 1.f);
  k_mm<192, 1><<<dim3(kHW / 64, kN), 256, 0, stream>>>(w10b, t9Tb, x, t12b, 1.f);
  k_corr<<<dim3(kNPC, kN), 256, 0, stream>>>(t12b, t6b, part);
  k_redM<<<kN * kC * kC / 256, 256, 0, stream>>>(part, Mb);
  k_mm<128, 2><<<dim3(kHW / 64, kN), 256, 0, stream>>>(Mb, xT, nullptr, out, scale);
}

// Round 3
// 104.579 us; speedup vs baseline: 1.6881x; 1.4910x over previous
//
#include <hip/hip_runtime.h>
#include <cmath>

typedef short bf16x8 __attribute__((ext_vector_type(8)));
typedef float f32x4 __attribute__((ext_vector_type(4)));

namespace {
constexpr int kN   = 16;
constexpr int kC   = 128;
constexpr int kH   = 48;
constexpr int kW   = 48;
constexpr int kHW  = kH * kW;      // 2304
constexpr int kK9  = 192;          // 3*C/2
constexpr int kNPC = 18;           // correlation p-chunks
constexpr int kPCH = kHW / kNPC;   // 128
}

__device__ __forceinline__ unsigned short f2b(float f) {
  unsigned u = __builtin_bit_cast(unsigned, f);
  u = (u + 0x7FFFu + ((u >> 16) & 1u)) >> 16;   // RTNE
  return (unsigned short)u;
}

// ---------------------------------------------------------------------------
// w6 -> bf16
// ---------------------------------------------------------------------------
__global__ void k_wcvt(const float* __restrict__ w6, unsigned short* __restrict__ w6b) {
  const int i = blockIdx.x * 256 + threadIdx.x;
  if (i < kC * kC) w6b[i] = f2b(w6[i]);
}

// ---------------------------------------------------------------------------
// Weff[o][kk*5+j] = sum_{c2} w10[o][3*c2+kk] * w8[c2*5+j]   (fp32, 128x15)
// ---------------------------------------------------------------------------
__global__ void k_weff(const float* __restrict__ w10, const float* __restrict__ w8,
                       float* __restrict__ Weff) {
  const int idx = blockIdx.x * 256 + threadIdx.x;
  if (idx >= kC * 15) return;
  const int o = idx / 15, t = idx - o * 15;
  const int kk = t / 5, j = t - kk * 5;
  float s = 0.f;
#pragma unroll
  for (int c2 = 0; c2 < 64; ++c2)
    s = fmaf(w10[o * kK9 + 3 * c2 + kk], w8[c2 * 5 + j], s);
  Weff[idx] = s;
}

// ---------------------------------------------------------------------------
// Fused: xT[n][q][c] = bf16(x), t5T[n][q][c] = bf16(p5*max(-x, -x_wprev)),
//        t1[n][q] = max_c x.   Block = 128 c (fastest) x 2 q.
// ---------------------------------------------------------------------------
__global__ __launch_bounds__(256)
void k_xt5(const float* __restrict__ x, const float* __restrict__ p5,
           unsigned short* __restrict__ xT, unsigned short* __restrict__ t5T,
           float* __restrict__ t1) {
  const int tid = threadIdx.x;
  const int c = tid & 127;
  const int qi = tid >> 7;
  const int g = blockIdx.x * 2 + qi;          // n*kHW + q
  const int n = g / kHW, q = g - n * kHW;
  const int w = q % kW;
  const size_t xo = ((size_t)n * kC + c) * kHW + q;
  const float xv = x[xo];
  const float xp = x[xo + ((w == 0) ? (kW - 1) : -1)];
  const float t5 = p5[c * kHW + q] * fmaxf(-xv, -xp);
  const size_t to = (size_t)g * kC + c;
  xT[to] = f2b(xv);
  t5T[to] = f2b(t5);
  // channel max (128 c = 2 waves per q)
  float m = xv;
#pragma unroll
  for (int off = 32; off >= 1; off >>= 1)
    m = fmaxf(m, __shfl_xor(m, off, 64));
  __shared__ float red[4];
  if ((tid & 63) == 0) red[tid >> 6] = m;
  __syncthreads();
  if (tid < 2) t1[blockIdx.x * 2 + tid] = fmaxf(red[2 * tid], red[2 * tid + 1]);
}

// ---------------------------------------------------------------------------
// Fused t8/t9/t10/t11/t12:
//   t10[n,co,q] = sum_t Weff[co,t] * tap[t](n,q)   (15-tap dilated conv on t1)
//   t12[n,c,q]  = bf16( max(x[n,c,q], t10[n,(c-1)&127,q]) )
// Block: 256 q-tile x 32 channels (grid.z=4). Taps held in 15 VGPRs.
// ---------------------------------------------------------------------------
__global__ __launch_bounds__(256)
void k_t12(const float* __restrict__ x, const float* __restrict__ t1,
           const float* __restrict__ Weff, unsigned short* __restrict__ t12) {
  __shared__ float t1s[480];     // 10 rows x 48
  __shared__ float sW[32][15];
  const int tid = threadIdx.x;
  const int n = blockIdx.y;
  const int c0 = blockIdx.z * 32;
  const int q0 = blockIdx.x * 256;
  const int h0 = q0 / kW;
  const int hbase = h0 - 2;
  for (int i = tid; i < 480; i += 256) {
    const int r = hbase + i / kW, wc = i % kW;
    t1s[i] = (r >= 0 && r < kH) ? t1[n * kHW + r * kW + wc] : 0.f;
  }
  for (int i = tid; i < 32 * 15; i += 256) {
    const int ci = i / 15, t = i - ci * 15;
    sW[ci][t] = Weff[(((c0 + ci - 1) & (kC - 1)) * 15) + t];  // channel roll
  }
  __syncthreads();

  const int q = q0 + tid;
  const int h = q / kW, w = q - h * kW;
  const int hq = h - h0;
  float tap[15];
#pragma unroll
  for (int kk = 0; kk < 3; ++kk) {
    const int hh = h + 2 * kk - 2;
    const bool hv = (hh >= 0) && (hh < kH);
#pragma unroll
    for (int j = 0; j < 5; ++j) {
      const int ww = w + 3 * j - 6;
      tap[kk * 5 + j] = (hv && ww >= 0 && ww < kW) ? t1s[(hq + 2 * kk) * kW + ww] : 0.f;
    }
  }

#pragma unroll 4
  for (int i = 0; i < 32; ++i) {
    const int co = c0 + i;
    float v = 0.f;
#pragma unroll
    for (int t = 0; t < 15; ++t) v = fmaf(sW[i][t], tap[t], v);
    const size_t o = ((size_t)n * kC + co) * kHW + q;
    t12[o] = f2b(fmaxf(x[o], v));
  }
}

// ---------------------------------------------------------------------------
// bf16 MFMA GEMM: Out[n,m,q] = sum_k A[m,k]*B[n,q,k],  M=128, q-tile=64.
// A: [128][K] bf16 (MODE 2: per-batch, A + n*128*K). B: [n][q][K] bf16.
// MODE 0: store bf16 (t6). MODE 2: store fp32 scale*acc (final out).
// 4 waves; wave = 32 rows x 64 cols (2x4 16x16 tiles).
// ---------------------------------------------------------------------------
template <int K, int MODE>
__global__ __launch_bounds__(256)
void k_mm(const unsigned short* __restrict__ A, const unsigned short* __restrict__ B,
          void* __restrict__ Out, float scale) {
  constexpr int P  = K + 8;   // padded A row (bf16)
  constexpr int BP = 72;      // padded B row for 64-k chunk
  __shared__ unsigned short As[kC * P];
  __shared__ unsigned short Bs[64 * BP];
  const int tid = threadIdx.x;
  const int n = blockIdx.y;
  const int qbase = blockIdx.x * 64;
  const unsigned short* Ag = (MODE == 2) ? A + (size_t)n * kC * K : A;
  const unsigned short* Bg = B + ((size_t)n * kHW + qbase) * K;

  // stage all of A (128 x K)
  {
    const int m = tid >> 1, hf = tid & 1;
    const unsigned short* src = Ag + (size_t)m * K + hf * (K / 2);
    unsigned short* dst = &As[m * P + hf * (K / 2)];
#pragma unroll
    for (int i = 0; i < K / 16; ++i)
      *(bf16x8*)(dst + 8 * i) = *(const bf16x8*)(src + 8 * i);
  }

  const int wv = tid >> 6, lane = tid & 63;
  const int lr = lane & 15, lk = (lane >> 4) * 8;

  f32x4 acc[2][4];
#pragma unroll
  for (int i = 0; i < 2; ++i)
#pragma unroll
    for (int j = 0; j < 4; ++j) acc[i][j] = f32x4{0.f, 0.f, 0.f, 0.f};

  for (int ks = 0; ks < K; ks += 64) {
    if (ks) __syncthreads();
    {  // stage B chunk (64 q x 64 k)
      const int q = tid >> 2, seg = tid & 3;
      const unsigned short* src = Bg + (size_t)q * K + ks + seg * 16;
      unsigned short* dst = &Bs[q * BP + seg * 16];
      *(bf16x8*)dst = *(const bf16x8*)src;
      *(bf16x8*)(dst + 8) = *(const bf16x8*)(src + 8);
    }
    __syncthreads();
#pragma unroll
    for (int kt = 0; kt < 2; ++kt) {
      bf16x8 a[2], b[4];
#pragma unroll
      for (int mt = 0; mt < 2; ++mt)
        a[mt] = *(const bf16x8*)&As[(32 * wv + 16 * mt + lr) * P + ks + kt * 32 + lk];
#pragma unroll
      for (int nt = 0; nt < 4; ++nt)
        b[nt] = *(const bf16x8*)&Bs[(16 * nt + lr) * BP + kt * 32 + lk];
#pragma unroll
      for (int mt = 0; mt < 2; ++mt)
#pragma unroll
        for (int nt = 0; nt < 4; ++nt)
          acc[mt][nt] = __builtin_amdgcn_mfma_f32_16x16x32_bf16(
              a[mt], b[nt], acc[mt][nt], 0, 0, 0);
    }
  }

#pragma unroll
  for (int mt = 0; mt < 2; ++mt)
#pragma unroll
    for (int nt = 0; nt < 4; ++nt) {
      const int q = qbase + 16 * nt + lr;
#pragma unroll
      for (int r = 0; r < 4; ++r) {
        const int m = 32 * wv + 16 * mt + 4 * (lane >> 4) + r;
        const float v = acc[mt][nt][r];
        if (MODE == 0) {
          ((unsigned short*)Out)[((size_t)n * kC + m) * kHW + q] = f2b(v);
        } else {
          ((float*)Out)[((size_t)n * kC + m) * kHW + q] = scale * v;
        }
      }
    }
}

// ---------------------------------------------------------------------------
// Correlation partials: part[chunk,n,c,c'] = sum_{p in chunk} t12[n,c,p]*t6[n,c',p]
// Both operands in natural [c][p] bf16 layout. Block: 128x128 out, 4 waves 2x2.
// ---------------------------------------------------------------------------
__global__ __launch_bounds__(256)
void k_corr(const unsigned short* __restrict__ t12, const unsigned short* __restrict__ t6,
            float* __restrict__ part) {
  constexpr int PP = 40;
  __shared__ unsigned short As[kC * PP];
  __shared__ unsigned short Bs[kC * PP];
  const int tid = threadIdx.x;
  const int n = blockIdx.y;
  const int p0 = blockIdx.x * kPCH;
  const unsigned short* Ag = t12 + (size_t)n * kC * kHW + p0;
  const unsigned short* Bg = t6  + (size_t)n * kC * kHW + p0;
  const int wv = tid >> 6, lane = tid & 63;
  const int lr = lane & 15, lk = (lane >> 4) * 8;
  const int wr = (wv >> 1) * 64, wc = (wv & 1) * 64;

  f32x4 acc[4][4];
#pragma unroll
  for (int i = 0; i < 4; ++i)
#pragma unroll
    for (int j = 0; j < 4; ++j) acc[i][j] = f32x4{0.f, 0.f, 0.f, 0.f};

  for (int ks = 0; ks < kPCH; ks += 32) {
    if (ks) __syncthreads();
    {  // stage 128 x 32 slabs of both operands
      const int c = tid >> 1, hf = tid & 1;
      const unsigned short* sa = Ag + (size_t)c * kHW + ks + hf * 16;
      const unsigned short* sb = Bg + (size_t)c * kHW + ks + hf * 16;
      unsigned short* da = &As[c * PP + hf * 16];
      unsigned short* db = &Bs[c * PP + hf * 16];
      *(bf16x8*)da = *(const bf16x8*)sa;  *(bf16x8*)(da + 8) = *(const bf16x8*)(sa + 8);
      *(bf16x8*)db = *(const bf16x8*)sb;  *(bf16x8*)(db + 8) = *(const bf16x8*)(sb + 8);
    }
    __syncthreads();
    bf16x8 a[4], b[4];
#pragma unroll
    for (int i = 0; i < 4; ++i) {
      a[i] = *(const bf16x8*)&As[(wr + 16 * i + lr) * PP + lk];
      b[i] = *(const bf16x8*)&Bs[(wc + 16 * i + lr) * PP + lk];
    }
#pragma unroll
    for (int i = 0; i < 4; ++i)
#pragma unroll
      for (int j = 0; j < 4; ++j)
        acc[i][j] = __builtin_amdgcn_mfma_f32_16x16x32_bf16(a[i], b[j], acc[i][j], 0, 0, 0);
  }

  float* dst = part + ((size_t)blockIdx.x * kN + n) * (kC * kC);
#pragma unroll
  for (int i = 0; i < 4; ++i)
#pragma unroll
    for (int j = 0; j < 4; ++j)
#pragma unroll
      for (int r = 0; r < 4; ++r)
        dst[(wr + 16 * i + 4 * (lane >> 4) + r) * kC + wc + 16 * j + lr] = acc[i][j][r];
}

// ---------------------------------------------------------------------------
// Reduce kNPC partial slabs -> M bf16 [n][c][c']
// ---------------------------------------------------------------------------
__global__ void k_redM(const float* __restrict__ part, unsigned short* __restrict__ M) {
  const int idx = blockIdx.x * 256 + threadIdx.x;
  const int n = idx >> 14, r = idx & 16383;
  float s = 0.f;
#pragma unroll
  for (int ch = 0; ch < kNPC; ++ch)
    s += part[(((size_t)ch * kN + n) << 14) + r];
  M[idx] = f2b(s);
}

// ---------------------------------------------------------------------------
extern "C" void kernel_launch(void* const* d_in, const int* in_sizes, int n_in,
                              void* d_out, int out_size, void* d_ws, size_t ws_size,
                              hipStream_t stream) {
  const float* x   = (const float*)d_in[0];
  const float* p5  = (const float*)d_in[1];
  const float* w6  = (const float*)d_in[2];
  const float* w8  = (const float*)d_in[3];
  const float* w10 = (const float*)d_in[4];
  float* out = (float*)d_out;

  char* ws = (char*)d_ws;                                  // byte offsets
  unsigned short* xT   = (unsigned short*)(ws);            //  9,437,184
  unsigned short* t5T  = (unsigned short*)(ws + 9437184);  //  9,437,184
  unsigned short* t6b  = (unsigned short*)(ws + 18874368); //  9,437,184
  unsigned short* t12b = (unsigned short*)(ws + 28311552); //  9,437,184
  float*          part = (float*)(ws + 37748736);          // 18,874,368
  unsigned short* Mb   = (unsigned short*)(ws + 56623104); //    524,288
  float*          t1b  = (float*)(ws + 57147392);          //    147,456
  unsigned short* w6b  = (unsigned short*)(ws + 57294848); //     32,768
  float*          Weff = (float*)(ws + 57327616);          //      7,680  (end ~57.3 MB)

  const float scale = 1.0f / (sqrtf((float)kC) * sqrtf((float)kHW));

  k_wcvt<<<(kC * kC + 255) / 256, 256, 0, stream>>>(w6, w6b);
  k_weff<<<(kC * 15 + 255) / 256, 256, 0, stream>>>(w10, w8, Weff);
  k_xt5<<<kN * kHW / 2, 256, 0, stream>>>(x, p5, xT, t5T, t1b);
  k_t12<<<dim3(kHW / 256, kN, 4), 256, 0, stream>>>(x, t1b, Weff, t12b);
  k_mm<128, 0><<<dim3(kHW / 64, kN), 256, 0, stream>>>(w6b, t5T, t6b, 1.f);
  k_corr<<<dim3(kNPC, kN), 256, 0, stream>>>(t12b, t6b, part);
  k_redM<<<kN * kC * kC / 256, 256, 0, stream>>>(part, Mb);
  k_mm<128, 2><<<dim3(kHW / 64, kN), 256, 0, stream>>>(Mb, xT, out, scale);
}

// Round 4
// 70.058 us; speedup vs baseline: 2.5200x; 1.4928x over previous
//
#include <hip/hip_runtime.h>
#include <cmath>

typedef short bf16x8 __attribute__((ext_vector_type(8)));
typedef float f32x4 __attribute__((ext_vector_type(4)));

namespace {
constexpr int kN   = 16;
constexpr int kC   = 128;
constexpr int kH   = 48;
constexpr int kW   = 48;
constexpr int kHW  = kH * kW;      // 2304
constexpr int kK9  = 192;          // 3*C/2
constexpr int kNPC = 18;           // correlation p-chunks
constexpr int kPCH = kHW / kNPC;   // 128
constexpr int kLS  = 132;          // LDS row stride (floats) for transpose tiles
}

__device__ __forceinline__ unsigned short f2b(float f) {
  unsigned u = __builtin_bit_cast(unsigned, f);
  u = (u + 0x7FFFu + ((u >> 16) & 1u)) >> 16;   // RTNE
  return (unsigned short)u;
}

// LDS index for transpose tiles: [w][c] with XOR swizzle on the c-octet.
// swz depends on (w>>2)&3 so that the load phase (w = 4s+j, j=0..3) sees a
// per-thread-constant swizzle and the read phase keeps 8-float contiguity.
__device__ __forceinline__ int tidx(int w, int c) {
  return w * kLS + (c ^ (((w >> 2) & 3) << 3));
}

// ---------------------------------------------------------------------------
// w6 -> bf16
// ---------------------------------------------------------------------------
__global__ void k_wcvt(const float* __restrict__ w6, unsigned short* __restrict__ w6b) {
  const int i = blockIdx.x * 256 + threadIdx.x;
  if (i < kC * kC) w6b[i] = f2b(w6[i]);
}

// ---------------------------------------------------------------------------
// Weff[o][kk*5+j] = sum_{c2} w10[o][3*c2+kk] * w8[c2*5+j]   (fp32, 128x15)
// ---------------------------------------------------------------------------
__global__ void k_weff(const float* __restrict__ w10, const float* __restrict__ w8,
                       float* __restrict__ Weff) {
  const int idx = blockIdx.x * 256 + threadIdx.x;
  if (idx >= kC * 15) return;
  const int o = idx / 15, t = idx - o * 15;
  const int kk = t / 5, j = t - kk * 5;
  float s = 0.f;
#pragma unroll
  for (int c2 = 0; c2 < 64; ++c2)
    s = fmaf(w10[o * kK9 + 3 * c2 + kk], w8[c2 * 5 + j], s);
  Weff[idx] = s;
}

// ---------------------------------------------------------------------------
// p5T[q][c] = p5[c][q]  (fp32), LDS-tiled transpose, one block per h row.
// ---------------------------------------------------------------------------
__global__ __launch_bounds__(256)
void k_p5T(const float* __restrict__ p5, float* __restrict__ p5T) {
  __shared__ float Ls[kW * kLS];
  const int h = blockIdx.x;
  const int tid = threadIdx.x;
  // load 128c x 48w, coalesced along w
  for (int i = 0; i < 6; ++i) {
    const int idx = i * 256 + tid;          // 1536 float4s
    const int c = idx / 12, s = idx % 12;
    const float4 v = *(const float4*)(p5 + (size_t)c * kHW + h * kW + s * 4);
    const int sw = (s & 3) << 3;
    Ls[(4 * s + 0) * kLS + (c ^ sw)] = v.x;
    Ls[(4 * s + 1) * kLS + (c ^ sw)] = v.y;
    Ls[(4 * s + 2) * kLS + (c ^ sw)] = v.z;
    Ls[(4 * s + 3) * kLS + (c ^ sw)] = v.w;
  }
  __syncthreads();
  for (int i = 0; i < 3; ++i) {
    const int idx = i * 256 + tid;          // 768 = 48w x 16 c-octets
    const int w = idx >> 4, c = (idx & 15) * 8;
    const float* s = &Ls[tidx(w, c)];
    float4 a{s[0], s[1], s[2], s[3]}, b{s[4], s[5], s[6], s[7]};
    float* dst = p5T + ((size_t)(h * kW + w)) * kC + c;
    *(float4*)dst = a;
    *(float4*)(dst + 4) = b;
  }
}

// ---------------------------------------------------------------------------
// Fused transpose: xT[n][q][c]=bf16(x), t5T[n][q][c]=bf16(p5*max(-x,-x_wprev)),
// t1[n][q]=max_c x.  One block per (n,h) row; coalesced loads, LDS transpose.
// ---------------------------------------------------------------------------
__global__ __launch_bounds__(256)
void k_xt5(const float* __restrict__ x, const float* __restrict__ p5T,
           unsigned short* __restrict__ xT, unsigned short* __restrict__ t5T,
           float* __restrict__ t1) {
  __shared__ float Ls[kW * kLS];             // [w][c] swizzled, 25.3 KB
  const int b = blockIdx.x;                  // n*48 + h
  const int n = b / kH, h = b - n * kH;
  const int tid = threadIdx.x;
  const float* xrow = x + (size_t)n * kC * kHW + h * kW;
  for (int i = 0; i < 6; ++i) {
    const int idx = i * 256 + tid;
    const int c = idx / 12, s = idx % 12;
    const float4 v = *(const float4*)(xrow + (size_t)c * kHW + s * 4);
    const int sw = (s & 3) << 3;
    Ls[(4 * s + 0) * kLS + (c ^ sw)] = v.x;
    Ls[(4 * s + 1) * kLS + (c ^ sw)] = v.y;
    Ls[(4 * s + 2) * kLS + (c ^ sw)] = v.z;
    Ls[(4 * s + 3) * kLS + (c ^ sw)] = v.w;
  }
  __syncthreads();

  for (int i = 0; i < 3; ++i) {
    const int idx = i * 256 + tid;
    const int w = idx >> 4, c = (idx & 15) * 8;
    const int wp = (w == 0) ? (kW - 1) : (w - 1);
    const float* sv = &Ls[tidx(w, c)];
    const float* sp = &Ls[tidx(wp, c)];
    const int q = h * kW + w;
    const float* pv = p5T + (size_t)q * kC + c;

    unsigned short xb[8], tb[8];
    float m = -3.4e38f;
#pragma unroll
    for (int j = 0; j < 8; ++j) {
      const float xv = sv[j];
      const float t5 = pv[j] * fmaxf(-xv, -sp[j]);
      xb[j] = f2b(xv);
      tb[j] = f2b(t5);
      m = fmaxf(m, xv);
    }
    unsigned short* xd = xT + ((size_t)n * kHW + q) * kC + c;
    unsigned short* td = t5T + ((size_t)n * kHW + q) * kC + c;
    *(bf16x8*)xd = *(const bf16x8*)xb;
    *(bf16x8*)td = *(const bf16x8*)tb;
    // channel max over the 16 lanes covering this w
#pragma unroll
    for (int off = 1; off < 16; off <<= 1)
      m = fmaxf(m, __shfl_xor(m, off, 16));
    if ((tid & 15) == 0) t1[(size_t)n * kHW + q] = m;
  }
}

// ---------------------------------------------------------------------------
// Fused t8/t9/t10/t11/t12:
//   t10[n,co,q] = sum_t Weff[co,t] * tap[t](n,q)   (15-tap dilated conv on t1)
//   t12[n,c,q]  = bf16( max(x[n,c,q], t10[n,(c-1)&127,q]) )
// ---------------------------------------------------------------------------
__global__ __launch_bounds__(256)
void k_t12(const float* __restrict__ x, const float* __restrict__ t1,
           const float* __restrict__ Weff, unsigned short* __restrict__ t12) {
  __shared__ float t1s[480];     // 10 rows x 48
  __shared__ float sW[32][15];
  const int tid = threadIdx.x;
  const int n = blockIdx.y;
  const int c0 = blockIdx.z * 32;
  const int q0 = blockIdx.x * 256;
  const int h0 = q0 / kW;
  const int hbase = h0 - 2;
  for (int i = tid; i < 480; i += 256) {
    const int r = hbase + i / kW, wc = i % kW;
    t1s[i] = (r >= 0 && r < kH) ? t1[n * kHW + r * kW + wc] : 0.f;
  }
  for (int i = tid; i < 32 * 15; i += 256) {
    const int ci = i / 15, t = i - ci * 15;
    sW[ci][t] = Weff[(((c0 + ci - 1) & (kC - 1)) * 15) + t];  // channel roll
  }
  __syncthreads();

  const int q = q0 + tid;
  const int h = q / kW, w = q - h * kW;
  const int hq = h - h0;
  float tap[15];
#pragma unroll
  for (int kk = 0; kk < 3; ++kk) {
    const int hh = h + 2 * kk - 2;
    const bool hv = (hh >= 0) && (hh < kH);
#pragma unroll
    for (int j = 0; j < 5; ++j) {
      const int ww = w + 3 * j - 6;
      tap[kk * 5 + j] = (hv && ww >= 0 && ww < kW) ? t1s[(hq + 2 * kk) * kW + ww] : 0.f;
    }
  }

#pragma unroll 4
  for (int i = 0; i < 32; ++i) {
    const int co = c0 + i;
    float v = 0.f;
#pragma unroll
    for (int t = 0; t < 15; ++t) v = fmaf(sW[i][t], tap[t], v);
    const size_t o = ((size_t)n * kC + co) * kHW + q;
    t12[o] = f2b(fmaxf(x[o], v));
  }
}

// ---------------------------------------------------------------------------
// bf16 MFMA GEMM: Out[n,m,q] = sum_k A[m,k]*B[n,q,k],  M=128, q-tile=64.
// MODE 0: store bf16 (t6). MODE 2: per-batch A, store fp32 scale*acc.
// ---------------------------------------------------------------------------
template <int K, int MODE>
__global__ __launch_bounds__(256)
void k_mm(const unsigned short* __restrict__ A, const unsigned short* __restrict__ B,
          void* __restrict__ Out, float scale) {
  constexpr int P  = K + 8;
  constexpr int BP = 72;
  __shared__ unsigned short As[kC * P];
  __shared__ unsigned short Bs[64 * BP];
  const int tid = threadIdx.x;
  const int n = blockIdx.y;
  const int qbase = blockIdx.x * 64;
  const unsigned short* Ag = (MODE == 2) ? A + (size_t)n * kC * K : A;
  const unsigned short* Bg = B + ((size_t)n * kHW + qbase) * K;

  {
    const int m = tid >> 1, hf = tid & 1;
    const unsigned short* src = Ag + (size_t)m * K + hf * (K / 2);
    unsigned short* dst = &As[m * P + hf * (K / 2)];
#pragma unroll
    for (int i = 0; i < K / 16; ++i)
      *(bf16x8*)(dst + 8 * i) = *(const bf16x8*)(src + 8 * i);
  }

  const int wv = tid >> 6, lane = tid & 63;
  const int lr = lane & 15, lk = (lane >> 4) * 8;

  f32x4 acc[2][4];
#pragma unroll
  for (int i = 0; i < 2; ++i)
#pragma unroll
    for (int j = 0; j < 4; ++j) acc[i][j] = f32x4{0.f, 0.f, 0.f, 0.f};

  for (int ks = 0; ks < K; ks += 64) {
    if (ks) __syncthreads();
    {
      const int q = tid >> 2, seg = tid & 3;
      const unsigned short* src = Bg + (size_t)q * K + ks + seg * 16;
      unsigned short* dst = &Bs[q * BP + seg * 16];
      *(bf16x8*)dst = *(const bf16x8*)src;
      *(bf16x8*)(dst + 8) = *(const bf16x8*)(src + 8);
    }
    __syncthreads();
#pragma unroll
    for (int kt = 0; kt < 2; ++kt) {
      bf16x8 a[2], b[4];
#pragma unroll
      for (int mt = 0; mt < 2; ++mt)
        a[mt] = *(const bf16x8*)&As[(32 * wv + 16 * mt + lr) * P + ks + kt * 32 + lk];
#pragma unroll
      for (int nt = 0; nt < 4; ++nt)
        b[nt] = *(const bf16x8*)&Bs[(16 * nt + lr) * BP + kt * 32 + lk];
#pragma unroll
      for (int mt = 0; mt < 2; ++mt)
#pragma unroll
        for (int nt = 0; nt < 4; ++nt)
          acc[mt][nt] = __builtin_amdgcn_mfma_f32_16x16x32_bf16(
              a[mt], b[nt], acc[mt][nt], 0, 0, 0);
    }
  }

#pragma unroll
  for (int mt = 0; mt < 2; ++mt)
#pragma unroll
    for (int nt = 0; nt < 4; ++nt) {
      const int q = qbase + 16 * nt + lr;
#pragma unroll
      for (int r = 0; r < 4; ++r) {
        const int m = 32 * wv + 16 * mt + 4 * (lane >> 4) + r;
        const float v = acc[mt][nt][r];
        if (MODE == 0) {
          ((unsigned short*)Out)[((size_t)n * kC + m) * kHW + q] = f2b(v);
        } else {
          ((float*)Out)[((size_t)n * kC + m) * kHW + q] = scale * v;
        }
      }
    }
}

// ---------------------------------------------------------------------------
// Correlation partials: part[chunk,n,c,c'] = sum_{p in chunk} t12[n,c,p]*t6[n,c',p]
// ---------------------------------------------------------------------------
__global__ __launch_bounds__(256)
void k_corr(const unsigned short* __restrict__ t12, const unsigned short* __restrict__ t6,
            float* __restrict__ part) {
  constexpr int PP = 40;
  __shared__ unsigned short As[kC * PP];
  __shared__ unsigned short Bs[kC * PP];
  const int tid = threadIdx.x;
  const int n = blockIdx.y;
  const int p0 = blockIdx.x * kPCH;
  const unsigned short* Ag = t12 + (size_t)n * kC * kHW + p0;
  const unsigned short* Bg = t6  + (size_t)n * kC * kHW + p0;
  const int wv = tid >> 6, lane = tid & 63;
  const int lr = lane & 15, lk = (lane >> 4) * 8;
  const int wr = (wv >> 1) * 64, wc = (wv & 1) * 64;

  f32x4 acc[4][4];
#pragma unroll
  for (int i = 0; i < 4; ++i)
#pragma unroll
    for (int j = 0; j < 4; ++j) acc[i][j] = f32x4{0.f, 0.f, 0.f, 0.f};

  for (int ks = 0; ks < kPCH; ks += 32) {
    if (ks) __syncthreads();
    {
      const int c = tid >> 1, hf = tid & 1;
      const unsigned short* sa = Ag + (size_t)c * kHW + ks + hf * 16;
      const unsigned short* sb = Bg + (size_t)c * kHW + ks + hf * 16;
      unsigned short* da = &As[c * PP + hf * 16];
      unsigned short* db = &Bs[c * PP + hf * 16];
      *(bf16x8*)da = *(const bf16x8*)sa;  *(bf16x8*)(da + 8) = *(const bf16x8*)(sa + 8);
      *(bf16x8*)db = *(const bf16x8*)sb;  *(bf16x8*)(db + 8) = *(const bf16x8*)(sb + 8);
    }
    __syncthreads();
    bf16x8 a[4], b[4];
#pragma unroll
    for (int i = 0; i < 4; ++i) {
      a[i] = *(const bf16x8*)&As[(wr + 16 * i + lr) * PP + lk];
      b[i] = *(const bf16x8*)&Bs[(wc + 16 * i + lr) * PP + lk];
    }
#pragma unroll
    for (int i = 0; i < 4; ++i)
#pragma unroll
      for (int j = 0; j < 4; ++j)
        acc[i][j] = __builtin_amdgcn_mfma_f32_16x16x32_bf16(a[i], b[j], acc[i][j], 0, 0, 0);
  }

  float* dst = part + ((size_t)blockIdx.x * kN + n) * (kC * kC);
#pragma unroll
  for (int i = 0; i < 4; ++i)
#pragma unroll
    for (int j = 0; j < 4; ++j)
#pragma unroll
      for (int r = 0; r < 4; ++r)
        dst[(wr + 16 * i + 4 * (lane >> 4) + r) * kC + wc + 16 * j + lr] = acc[i][j][r];
}

// ---------------------------------------------------------------------------
// Reduce kNPC partial slabs -> M bf16 [n][c][c']
// ---------------------------------------------------------------------------
__global__ void k_redM(const float* __restrict__ part, unsigned short* __restrict__ M) {
  const int idx = blockIdx.x * 256 + threadIdx.x;
  const int n = idx >> 14, r = idx & 16383;
  float s = 0.f;
#pragma unroll
  for (int ch = 0; ch < kNPC; ++ch)
    s += part[(((size_t)ch * kN + n) << 14) + r];
  M[idx] = f2b(s);
}

// ---------------------------------------------------------------------------
extern "C" void kernel_launch(void* const* d_in, const int* in_sizes, int n_in,
                              void* d_out, int out_size, void* d_ws, size_t ws_size,
                              hipStream_t stream) {
  const float* x   = (const float*)d_in[0];
  const float* p5  = (const float*)d_in[1];
  const float* w6  = (const float*)d_in[2];
  const float* w8  = (const float*)d_in[3];
  const float* w10 = (const float*)d_in[4];
  float* out = (float*)d_out;

  char* ws = (char*)d_ws;                                  // byte offsets
  unsigned short* xT   = (unsigned short*)(ws);            //  9,437,184
  unsigned short* t5T  = (unsigned short*)(ws + 9437184);  //  9,437,184
  unsigned short* t6b  = (unsigned short*)(ws + 18874368); //  9,437,184
  unsigned short* t12b = (unsigned short*)(ws + 28311552); //  9,437,184
  float*          part = (float*)(ws + 37748736);          // 18,874,368
  unsigned short* Mb   = (unsigned short*)(ws + 56623104); //    524,288
  float*          t1b  = (float*)(ws + 57147392);          //    147,456
  unsigned short* w6b  = (unsigned short*)(ws + 57294848); //     32,768
  float*          Weff = (float*)(ws + 57327616);          //      7,680
  float*          p5T  = (float*)(ws + 57335296);          //  1,179,648 (end ~58.5 MB)

  const float scale = 1.0f / (sqrtf((float)kC) * sqrtf((float)kHW));

  k_wcvt<<<(kC * kC + 255) / 256, 256, 0, stream>>>(w6, w6b);
  k_weff<<<(kC * 15 + 255) / 256, 256, 0, stream>>>(w10, w8, Weff);
  k_p5T<<<kH, 256, 0, stream>>>(p5, p5T);
  k_xt5<<<kN * kH, 256, 0, stream>>>(x, p5T, xT, t5T, t1b);
  k_t12<<<dim3(kHW / 256, kN, 4), 256, 0, stream>>>(x, t1b, Weff, t12b);
  k_mm<128, 0><<<dim3(kHW / 64, kN), 256, 0, stream>>>(w6b, t5T, t6b, 1.f);
  k_corr<<<dim3(kNPC, kN), 256, 0, stream>>>(t12b, t6b, part);
  k_redM<<<kN * kC * kC / 256, 256, 0, stream>>>(part, Mb);
  k_mm<128, 2><<<dim3(kHW / 64, kN), 256, 0, stream>>>(Mb, xT, out, scale);
}

// Round 6
// 49.487 us; speedup vs baseline: 3.5675x; 1.4157x over previous
//
#include <hip/hip_runtime.h>
#include <cmath>

typedef short bf16x8 __attribute__((ext_vector_type(8)));
typedef float f32x4 __attribute__((ext_vector_type(4)));

namespace {
constexpr int kN   = 16;
constexpr int kC   = 128;
constexpr int kH   = 48;
constexpr int kW   = 48;
constexpr int kHW  = kH * kW;      // 2304
constexpr int kK9  = 192;          // 3*C/2
constexpr int kNPC = 18;           // correlation p-chunks
constexpr int kPCH = kHW / kNPC;   // 128
constexpr int kLS  = 132;          // LDS row stride (floats) for fp32 transpose tile
constexpr int kPA  = 136;          // bf16 LDS stride (272B, 16B-aligned, 2-way bank alias only)
}

__device__ __forceinline__ unsigned short f2b(float f) {
  unsigned u = __builtin_bit_cast(unsigned, f);
  u = (u + 0x7FFFu + ((u >> 16) & 1u)) >> 16;   // RTNE
  return (unsigned short)u;
}

// LDS index for fp32 transpose tile: [w][c] with XOR swizzle on the c-octet.
__device__ __forceinline__ int tidx(int w, int c) {
  return w * kLS + (c ^ (((w >> 2) & 3) << 3));
}

// ---------------------------------------------------------------------------
// Fused prep: blocks 0..47 p5T transpose; 48..111 w6->bf16; 112..119 Weff.
// ---------------------------------------------------------------------------
__global__ __launch_bounds__(256)
void k_prep(const float* __restrict__ p5, const float* __restrict__ w6,
            const float* __restrict__ w10, const float* __restrict__ w8,
            float* __restrict__ p5T, unsigned short* __restrict__ w6b,
            float* __restrict__ Weff) {
  const int tid = threadIdx.x;
  const int bb = blockIdx.x;
  if (bb < 48) {                     // p5T[q][c] = p5[c][q]
    __shared__ float Ls[kW * kLS];
    const int h = bb;
    for (int i = 0; i < 6; ++i) {
      const int idx = i * 256 + tid;
      const int c = idx / 12, s = idx % 12;
      const float4 v = *(const float4*)(p5 + (size_t)c * kHW + h * kW + s * 4);
      const int sw = (s & 3) << 3;
      Ls[(4 * s + 0) * kLS + (c ^ sw)] = v.x;
      Ls[(4 * s + 1) * kLS + (c ^ sw)] = v.y;
      Ls[(4 * s + 2) * kLS + (c ^ sw)] = v.z;
      Ls[(4 * s + 3) * kLS + (c ^ sw)] = v.w;
    }
    __syncthreads();
    for (int i = 0; i < 3; ++i) {
      const int idx = i * 256 + tid;
      const int w = idx >> 4, c = (idx & 15) * 8;
      const float* s = &Ls[tidx(w, c)];
      float4 a{s[0], s[1], s[2], s[3]}, b{s[4], s[5], s[6], s[7]};
      float* dst = p5T + ((size_t)(h * kW + w)) * kC + c;
      *(float4*)dst = a;
      *(float4*)(dst + 4) = b;
    }
  } else if (bb < 112) {             // w6 -> bf16
    const int i = (bb - 48) * 256 + tid;
    w6b[i] = f2b(w6[i]);
  } else {                           // Weff[o][kk*5+j]
    const int idx = (bb - 112) * 256 + tid;
    if (idx < kC * 15) {
      const int o = idx / 15, t = idx - o * 15;
      const int kk = t / 5, j = t - kk * 5;
      float s = 0.f;
#pragma unroll
      for (int c2 = 0; c2 < 64; ++c2)
        s = fmaf(w10[o * kK9 + 3 * c2 + kk], w8[c2 * 5 + j], s);
      Weff[idx] = s;
    }
  }
}

// ---------------------------------------------------------------------------
// Fused transpose + t6 GEMM. One block per (n,h). Linear barrier structure:
// phase1 writes Ls/w6s -> sync -> phase2 reads Ls, writes t5s/xT/t1 -> sync
// -> phase3 reads w6s/t5s, MFMA, writes t6.
// ---------------------------------------------------------------------------
__global__ __launch_bounds__(256)
void k_xt5t6(const float* __restrict__ x, const float* __restrict__ p5T,
             const unsigned short* __restrict__ w6b,
             unsigned short* __restrict__ xT, float* __restrict__ t1,
             unsigned short* __restrict__ t6) {
  __shared__ __align__(16) float Ls[kW * kLS];             // 25.3 KB
  __shared__ __align__(16) unsigned short w6s[kC * kPA];   // 34.8 KB
  __shared__ __align__(16) unsigned short t5s[kW * kPA];   // 13.1 KB
  const int b = blockIdx.x;                  // n*48 + h
  const int n = b / kH, h = b - n * kH;
  const int tid = threadIdx.x;
  const float* xrow = x + (size_t)n * kC * kHW + h * kW;
  // phase 1
  for (int i = 0; i < 6; ++i) {
    const int idx = i * 256 + tid;
    const int c = idx / 12, s = idx % 12;
    const float4 v = *(const float4*)(xrow + (size_t)c * kHW + s * 4);
    const int sw = (s & 3) << 3;
    Ls[(4 * s + 0) * kLS + (c ^ sw)] = v.x;
    Ls[(4 * s + 1) * kLS + (c ^ sw)] = v.y;
    Ls[(4 * s + 2) * kLS + (c ^ sw)] = v.z;
    Ls[(4 * s + 3) * kLS + (c ^ sw)] = v.w;
  }
  for (int i = 0; i < 8; ++i) {
    const int f = i * 256 + tid;
    const int o = f >> 4, seg = (f & 15) * 8;
    *(bf16x8*)&w6s[o * kPA + seg] = *(const bf16x8*)(w6b + o * kC + seg);
  }
  __syncthreads();

  // phase 2
  for (int i = 0; i < 3; ++i) {
    const int idx = i * 256 + tid;
    const int w = idx >> 4, c = (idx & 15) * 8;
    const int wp = (w == 0) ? (kW - 1) : (w - 1);
    const float* sv = &Ls[tidx(w, c)];
    const float* sp = &Ls[tidx(wp, c)];
    const int q = h * kW + w;
    const float* pv = p5T + (size_t)q * kC + c;

    unsigned short xb[8], tb[8];
    float m = -3.4e38f;
#pragma unroll
    for (int j = 0; j < 8; ++j) {
      const float xv = sv[j];
      const float t5 = pv[j] * fmaxf(-xv, -sp[j]);
      xb[j] = f2b(xv);
      tb[j] = f2b(t5);
      m = fmaxf(m, xv);
    }
    *(bf16x8*)(xT + ((size_t)n * kHW + q) * kC + c) = *(const bf16x8*)xb;
    *(bf16x8*)&t5s[w * kPA + c] = *(const bf16x8*)tb;
#pragma unroll
    for (int off = 1; off < 16; off <<= 1)
      m = fmaxf(m, __shfl_xor(m, off, 16));
    if ((tid & 15) == 0) t1[(size_t)n * kHW + q] = m;
  }
  __syncthreads();

  // phase 3: t6 = w6 @ t5  (m=128 o, n=48 q, k=128 c)
  const int wv = tid >> 6, lane = tid & 63;
  const int lr = lane & 15, lk = (lane >> 4) * 8;
  f32x4 acc[2][3];
#pragma unroll
  for (int i = 0; i < 2; ++i)
#pragma unroll
    for (int j = 0; j < 3; ++j) acc[i][j] = f32x4{0.f, 0.f, 0.f, 0.f};
#pragma unroll
  for (int ks = 0; ks < kC; ks += 32) {
    bf16x8 a[2], bf[3];
#pragma unroll
    for (int mt = 0; mt < 2; ++mt)
      a[mt] = *(const bf16x8*)&w6s[(32 * wv + 16 * mt + lr) * kPA + ks + lk];
#pragma unroll
    for (int nt = 0; nt < 3; ++nt)
      bf[nt] = *(const bf16x8*)&t5s[(16 * nt + lr) * kPA + ks + lk];
#pragma unroll
    for (int mt = 0; mt < 2; ++mt)
#pragma unroll
      for (int nt = 0; nt < 3; ++nt)
        acc[mt][nt] = __builtin_amdgcn_mfma_f32_16x16x32_bf16(a[mt], bf[nt], acc[mt][nt], 0, 0, 0);
  }
#pragma unroll
  for (int mt = 0; mt < 2; ++mt)
#pragma unroll
    for (int nt = 0; nt < 3; ++nt) {
      const int q = h * kW + 16 * nt + lr;
#pragma unroll
      for (int r = 0; r < 4; ++r) {
        const int o = 32 * wv + 16 * mt + 4 * (lane >> 4) + r;
        t6[((size_t)n * kC + o) * kHW + q] = f2b(acc[mt][nt][r]);
      }
    }
}

// ---------------------------------------------------------------------------
// Fused t8..t12 + correlation partials. RACE-FREE STRUCTURE:
//   stage t1s + sW + FULL B tile (LDS writes only) -> sync ->
//   build t12s (reads t1s/sW/x, writes disjoint t12s) -> sync ->
//   MFMA loop (pure LDS reads, NO internal barriers).
// ---------------------------------------------------------------------------
__global__ __launch_bounds__(256)
void k_corr(const float* __restrict__ x, const float* __restrict__ t1,
            const float* __restrict__ Weff, const unsigned short* __restrict__ t6,
            float* __restrict__ part) {
  __shared__ __align__(16) unsigned short t12s[kC * kPA];   // 34.8 KB
  __shared__ __align__(16) unsigned short Bsf[kC * kPA];    // 34.8 KB (full 128x128)
  __shared__ __align__(16) float t1s[8 * 60];               // 1.9 KB
  __shared__ float sW[kC][15];                              // 7.5 KB
  const int tid = threadIdx.x;
  const int n = blockIdx.y;
  const int p0 = blockIdx.x * kPCH;
  const int h_lo = p0 / kW;
  const unsigned short* Bg = t6 + (size_t)n * kC * kHW + p0;

  // ---- stage phase (LDS writes only) ----
  for (int i = tid; i < 8 * 60; i += 256) {
    const int r = i / 60, cc = i - r * 60;
    const int hh = h_lo - 2 + r, ww = cc - 6;
    t1s[i] = (hh >= 0 && hh < kH && ww >= 0 && ww < kW) ? t1[n * kHW + hh * kW + ww] : 0.f;
  }
  for (int i = tid; i < kC * 15; i += 256) {
    const int c = i / 15, t = i - c * 15;
    sW[c][t] = Weff[((c - 1) & (kC - 1)) * 15 + t];        // channel roll
  }
#pragma unroll
  for (int i = 0; i < 8; ++i) {
    const int f = i * 256 + tid;
    const int c = f >> 4, seg = (f & 15) * 8;
    *(bf16x8*)&Bsf[c * kPA + seg] = *(const bf16x8*)(Bg + (size_t)c * kHW + seg);
  }
  __syncthreads();

  // ---- t12 tile build (reads t1s/sW/x; writes disjoint t12s cells) ----
  const float* xn = x + (size_t)n * kC * kHW;
  for (int it = 0; it < 8; ++it) {
    const int idx = it * 256 + tid;
    const int c = idx >> 4, p = (idx & 15) * 8;
    const int q = p0 + p;
    const int h = q / kW, w0 = q - h * kW;                 // w0 multiple of 8
    const int r0 = h - h_lo;                               // t1s row for kk=0 (=h-2)
    float tap[3][20];
#pragma unroll
    for (int kk = 0; kk < 3; ++kk) {
      const float* src = &t1s[(r0 + 2 * kk) * 60 + w0];    // col w0-6 at index w0
#pragma unroll
      for (int j4 = 0; j4 < 5; ++j4) {
        const float4 v = *(const float4*)(src + 4 * j4);
        tap[kk][4 * j4 + 0] = v.x; tap[kk][4 * j4 + 1] = v.y;
        tap[kk][4 * j4 + 2] = v.z; tap[kk][4 * j4 + 3] = v.w;
      }
    }
    float wr[15];
#pragma unroll
    for (int t = 0; t < 15; ++t) wr[t] = sW[c][t];
    const float* xp = xn + (size_t)c * kHW + q;
    const float4 xa = *(const float4*)xp;
    const float4 xb = *(const float4*)(xp + 4);
    const float xv[8] = {xa.x, xa.y, xa.z, xa.w, xb.x, xb.y, xb.z, xb.w};
    unsigned short o16[8];
#pragma unroll
    for (int dp = 0; dp < 8; ++dp) {
      float acc = 0.f;
#pragma unroll
      for (int kk = 0; kk < 3; ++kk)
#pragma unroll
        for (int j = 0; j < 5; ++j)
          acc = fmaf(wr[kk * 5 + j], tap[kk][3 * j + dp], acc);
      o16[dp] = f2b(fmaxf(xv[dp], acc));
    }
    *(bf16x8*)&t12s[c * kPA + p] = *(const bf16x8*)o16;
  }
  __syncthreads();

  // ---- MFMA: part[c][c'] = sum_p t12[c][p] * t6[c'][p]  (pure reads) ----
  const int wv = tid >> 6, lane = tid & 63;
  const int lr = lane & 15, lk = (lane >> 4) * 8;
  const int wr2 = (wv >> 1) * 64, wc2 = (wv & 1) * 64;
  f32x4 acc[4][4];
#pragma unroll
  for (int i = 0; i < 4; ++i)
#pragma unroll
    for (int j = 0; j < 4; ++j) acc[i][j] = f32x4{0.f, 0.f, 0.f, 0.f};

#pragma unroll
  for (int ks = 0; ks < kPCH; ks += 32) {
    bf16x8 a[4], bv[4];
#pragma unroll
    for (int i = 0; i < 4; ++i) {
      a[i]  = *(const bf16x8*)&t12s[(wr2 + 16 * i + lr) * kPA + ks + lk];
      bv[i] = *(const bf16x8*)&Bsf[(wc2 + 16 * i + lr) * kPA + ks + lk];
    }
#pragma unroll
    for (int i = 0; i < 4; ++i)
#pragma unroll
      for (int j = 0; j < 4; ++j)
        acc[i][j] = __builtin_amdgcn_mfma_f32_16x16x32_bf16(a[i], bv[j], acc[i][j], 0, 0, 0);
  }

  float* dst = part + ((size_t)blockIdx.x * kN + n) * (kC * kC);
#pragma unroll
  for (int i = 0; i < 4; ++i)
#pragma unroll
    for (int j = 0; j < 4; ++j)
#pragma unroll
      for (int r = 0; r < 4; ++r)
        dst[(wr2 + 16 * i + 4 * (lane >> 4) + r) * kC + wc2 + 16 * j + lr] = acc[i][j][r];
}

// ---------------------------------------------------------------------------
// Reduce kNPC partial slabs -> M bf16 [n][c][c']
// ---------------------------------------------------------------------------
__global__ __launch_bounds__(256)
void k_redM(const float* __restrict__ part, unsigned short* __restrict__ M) {
  const int idx = blockIdx.x * 256 + threadIdx.x;
  const int n = idx >> 14, r = idx & 16383;
  float s = 0.f;
#pragma unroll
  for (int ch = 0; ch < kNPC; ++ch)
    s += part[(((size_t)ch * kN + n) << 14) + r];
  M[idx] = f2b(s);
}

// ---------------------------------------------------------------------------
// Final GEMM: out[n,m,q] = scale * sum_k M[n,m,k] * xT[n,q,k]
// RACE-FREE: stage As + full Bs -> ONE sync -> barrier-free compute.
// ---------------------------------------------------------------------------
__global__ __launch_bounds__(256)
void k_out(const unsigned short* __restrict__ A, const unsigned short* __restrict__ B,
           float* __restrict__ Out, float scale) {
  constexpr int K = 128;
  __shared__ __align__(16) unsigned short As[kC * kPA];    // 34.8 KB
  __shared__ __align__(16) unsigned short Bs[64 * kPA];    // 17.4 KB
  const int tid = threadIdx.x;
  const int n = blockIdx.y;
  const int qbase = blockIdx.x * 64;
  const unsigned short* Ag = A + (size_t)n * kC * K;
  const unsigned short* Bg = B + ((size_t)n * kHW + qbase) * K;

  {
    const int m = tid >> 1, hf = tid & 1;
    const unsigned short* src = Ag + (size_t)m * K + hf * 64;
    unsigned short* dst = &As[m * kPA + hf * 64];
#pragma unroll
    for (int i = 0; i < 8; ++i)
      *(bf16x8*)(dst + 8 * i) = *(const bf16x8*)(src + 8 * i);
  }
#pragma unroll
  for (int i = 0; i < 4; ++i) {
    const int f = i * 256 + tid;
    const int q = f >> 4, seg = (f & 15) * 8;
    *(bf16x8*)&Bs[q * kPA + seg] = *(const bf16x8*)(Bg + (size_t)q * K + seg);
  }
  __syncthreads();

  const int wv = tid >> 6, lane = tid & 63;
  const int lr = lane & 15, lk = (lane >> 4) * 8;

  f32x4 acc[2][4];
#pragma unroll
  for (int i = 0; i < 2; ++i)
#pragma unroll
    for (int j = 0; j < 4; ++j) acc[i][j] = f32x4{0.f, 0.f, 0.f, 0.f};

#pragma unroll
  for (int ks = 0; ks < K; ks += 32) {
    bf16x8 a[2], b[4];
#pragma unroll
    for (int mt = 0; mt < 2; ++mt)
      a[mt] = *(const bf16x8*)&As[(32 * wv + 16 * mt + lr) * kPA + ks + lk];
#pragma unroll
    for (int nt = 0; nt < 4; ++nt)
      b[nt] = *(const bf16x8*)&Bs[(16 * nt + lr) * kPA + ks + lk];
#pragma unroll
    for (int mt = 0; mt < 2; ++mt)
#pragma unroll
      for (int nt = 0; nt < 4; ++nt)
        acc[mt][nt] = __builtin_amdgcn_mfma_f32_16x16x32_bf16(
            a[mt], b[nt], acc[mt][nt], 0, 0, 0);
  }

#pragma unroll
  for (int mt = 0; mt < 2; ++mt)
#pragma unroll
    for (int nt = 0; nt < 4; ++nt) {
      const int q = qbase + 16 * nt + lr;
#pragma unroll
      for (int r = 0; r < 4; ++r) {
        const int m = 32 * wv + 16 * mt + 4 * (lane >> 4) + r;
        Out[((size_t)n * kC + m) * kHW + q] = scale * acc[mt][nt][r];
      }
    }
}

// ---------------------------------------------------------------------------
extern "C" void kernel_launch(void* const* d_in, const int* in_sizes, int n_in,
                              void* d_out, int out_size, void* d_ws, size_t ws_size,
                              hipStream_t stream) {
  const float* x   = (const float*)d_in[0];
  const float* p5  = (const float*)d_in[1];
  const float* w6  = (const float*)d_in[2];
  const float* w8  = (const float*)d_in[3];
  const float* w10 = (const float*)d_in[4];
  float* out = (float*)d_out;

  char* ws = (char*)d_ws;                                  // byte offsets
  unsigned short* xT   = (unsigned short*)(ws);            //  9,437,184
  unsigned short* t6b  = (unsigned short*)(ws + 9437184);  //  9,437,184
  float*          part = (float*)(ws + 18874368);          // 18,874,368
  unsigned short* Mb   = (unsigned short*)(ws + 37748736); //    524,288
  float*          t1b  = (float*)(ws + 38273024);          //    147,456
  unsigned short* w6b  = (unsigned short*)(ws + 38420480); //     32,768
  float*          Weff = (float*)(ws + 38453248);          //      7,680
  float*          p5T  = (float*)(ws + 38460928);          //  1,179,648 (end ~39.6 MB)

  const float scale = 1.0f / (sqrtf((float)kC) * sqrtf((float)kHW));

  k_prep<<<120, 256, 0, stream>>>(p5, w6, w10, w8, p5T, w6b, Weff);
  k_xt5t6<<<kN * kH, 256, 0, stream>>>(x, p5T, w6b, xT, t1b, t6b);
  k_corr<<<dim3(kNPC, kN), 256, 0, stream>>>(x, t1b, Weff, t6b, part);
  k_redM<<<kN * kC * kC / 256, 256, 0, stream>>>(part, Mb);
  k_out<<<dim3(kHW / 64, kN), 256, 0, stream>>>(Mb, xT, out, scale);
}